// Round 14
// baseline (74.513 us; speedup 1.0000x reference)
//
#include <hip/hip_runtime.h>
#include <math.h>

#define BATCH 32
#define PTS   64
#define NPHI  8192

// ---------- fp64-core sincos (phi only — twice per thread, setup) ----------
// Validated bit-faithful to numpy/JAX fp32 trig in rounds 3-13. q0/q1 feed
// every edge with pole-amplified sensitivity (sin phi near 1: ulp 6e-8),
// so phi's trig must stay at fp64 accuracy. ~2% of thread runtime.
__device__ __forceinline__ void sincosf_f64(float xf, float* s, float* c) {
    const double PIO2_HI = 1.57079632679489661923e+00;
    const double PIO2_LO = 6.12323399573676603587e-17;

    const float kf = __builtin_rintf(__fmul_rn(xf, 0.63661977236758138243f));
    const int   qi = (int)kf;
    const double kd = (double)kf;
    const double x  = (double)xf;

    double r = __builtin_fma(-kd, PIO2_HI, x);
    r = __builtin_fma(-kd, PIO2_LO, r);
    const double r2 = r * r;

    double ps = -2.50507602534068634195e-08;
    ps = __builtin_fma(ps, r2,  2.75573137070700676789e-06);
    ps = __builtin_fma(ps, r2, -1.98412698298579493134e-04);
    ps = __builtin_fma(ps, r2,  8.33333333332248946124e-03);
    ps = __builtin_fma(ps, r2, -1.66666666666666324348e-01);
    const double sinr = __builtin_fma(r * r2, ps, r);

    double pc =  2.08757232129817482790e-09;
    pc = __builtin_fma(pc, r2, -2.75573143513906633035e-07);
    pc = __builtin_fma(pc, r2,  2.48015872894767294178e-05);
    pc = __builtin_fma(pc, r2, -1.38888888888741095749e-03);
    pc = __builtin_fma(pc, r2,  4.16666666666666019037e-02);
    const double cosr = __builtin_fma(r2 * r2, pc, __builtin_fma(-0.5, r2, 1.0));

    const float sf = (float)sinr, cf = (float)cosr;
    const bool sw = (qi & 1);
    const float ss = sw ? cf : sf;
    const float cc = sw ? sf : cf;
    *s = (qi & 2)       ? -ss : ss;
    *c = ((qi + 1) & 2) ? -cc : cc;
}

// ---------- fp32 sincos for edge args (rounds 7-13 validated, 0.1988525) ----
// Same arithmetic as R7-R13 (coeffs, op order); sign-via-xor quadrant
// lowering validated BIT-IDENTICAL in R12 ((qi&2)?-v:v == v ^ sign-bit).
// Error structure (R6/R7): high-amplification n (scale large, phi~pi/2)
// have tiny args -> kf=0, exact reduction, compensated cos (1+u) matches
// numpy's fp32 bits; kf!=0 only where scale <= ~40 (dev ~1e-2 amplified).
__device__ __forceinline__ void sincos32(float x, float* s, float* c) {
    const float C1 = 1.5707969665527344f;    // exact-product reduction const
    const float C2 = -6.3975783777e-7f;      // pi/2 - C1

    const float kf = __builtin_rintf(x * 0.63661977236758f);
    const int   qi = (int)kf;
    const float r1 = __builtin_fmaf(-kf, C1, x);   // exact
    const float r  = __builtin_fmaf(-kf, C2, r1);
    const float r2 = r * r;

    float ps = __builtin_fmaf(2.75573137e-06f, r2, -1.98412698e-04f);
    ps = __builtin_fmaf(ps, r2,  8.33333333e-03f);
    ps = __builtin_fmaf(ps, r2, -1.66666667e-01f);
    const float sr = __builtin_fmaf(r * r2, ps, r);

    float pc = __builtin_fmaf(-2.75573144e-07f, r2, 2.48015873e-05f);
    pc = __builtin_fmaf(pc, r2, -1.38888889e-03f);
    pc = __builtin_fmaf(pc, r2,  4.16666667e-02f);
    const float u  = __builtin_fmaf(r2 * r2, pc, -(0.5f * r2));
    const float cr = 1.0f + u;

    const bool sw = (qi & 1);
    const float ss = sw ? cr : sr;
    const float cc = sw ? sr : cr;
    const unsigned ssign = ((unsigned)qi << 30) & 0x80000000u;        // qi&2
    const unsigned csign = ((unsigned)(qi + 1) << 30) & 0x80000000u;  // (qi+1)&2
    *s = __uint_as_float(__float_as_uint(ss) ^ ssign);
    *c = __uint_as_float(__float_as_uint(cc) ^ csign);
}

// R10's VALIDATED OPTIMUM structure (21.9us measured via R10 probe):
// one thread per (b, n-pair), streams a=n0, b=n0+4096, ALL 64 edges;
// 512 blocks -> 2 waves/SIMD (occupancy sweep R9/R12/R13 proved both
// directions away from this point regress). Changes vs R10: sign-xor
// sincos lowering (R12 bit-validated), unroll 16 w/ plain addressing
// (less loop/branch overhead than unroll 4), no modulo prefetch.
//
// Per-stream arithmetic op-for-op identical to R10 (validated absmax
// 0.1988525): dp exact 3-op fp32, ddq/ddqc exact, bit-exact 1e-4 mask,
// rcp + fp32 accumulation in edge order 0..63, scale applied at the end.
__global__ __launch_bounds__(256, 2) void scatter_polygon_kernel(
    const float* __restrict__ points,   // [B, P, 2]
    const float* __restrict__ phi,      // [N]
    float* __restrict__ out)            // [B, 2, N]
{
    __shared__ float2 spts[PTS];

    const int b = blockIdx.y;
    const int tid = threadIdx.x;
    const int n0 = blockIdx.x * 256 + tid;
    const int n1 = n0 + NPHI / 2;

    if (tid < PTS) {
        spts[tid] = reinterpret_cast<const float2*>(points)[b * PTS + tid];
    }
    __syncthreads();

    float q0a, q1a, sca, q0b, q1b, scb;
    {
        float s, c;
        sincosf_f64(phi[n0], &s, &c);
        q0a = c; q1a = __fsub_rn(s, 1.0f);
        sca = 1.0f / fabsf(__fadd_rn(__fmul_rn(q0a, q0a), __fmul_rn(q1a, q1a)));
        sincosf_f64(phi[n1], &s, &c);
        q0b = c; q1b = __fsub_rn(s, 1.0f);
        scb = 1.0f / fabsf(__fadd_rn(__fmul_rn(q0b, q0b), __fmul_rn(q1b, q1b)));
    }

    const float2 pv = spts[PTS - 1];            // prev vertex (roll by 1)
    float xp = pv.x, yp = pv.y;
    float s0a, c0a, s0b, c0b;
    sincos32(__fadd_rn(__fmul_rn(xp, q0a), __fmul_rn(yp, q1a)), &s0a, &c0a);
    sincos32(__fadd_rn(__fmul_rn(xp, q0b), __fmul_rn(yp, q1b)), &s0b, &c0b);

    float aRa = 0.0f, aIa = 0.0f, aRb = 0.0f, aIb = 0.0f;

    #pragma unroll 16
    for (int p = 0; p < PTS; ++p) {
        const float2 v = spts[p];
        const float dx = __fsub_rn(v.x, xp);    // n-independent: shared
        const float dy = __fsub_rn(v.y, yp);

        {   // stream a (n0) — op-for-op R10 arithmetic
            const float dp = __fadd_rn(__fmul_rn(v.x, q0a), __fmul_rn(v.y, q1a));
            float s1, c1;
            sincos32(dp, &s1, &c1);
            const float ddq  = __fadd_rn(__fmul_rn(dx, q0a), __fmul_rn(dy, q1a));
            const float ddqc = __fsub_rn(__fmul_rn(dy, q0a), __fmul_rn(dx, q1a));
            const bool  m1  = (fabsf(ddq) >= 1e-4f);
            const float inv = __builtin_amdgcn_rcpf(ddq);
            const float dR = __fsub_rn(c0a, c1);
            const float dI = __fsub_rn(s0a, s1);
            const float gR = m1 ? (dR * inv) : s0a;
            const float gI = m1 ? (dI * inv) : (-c0a);
            aRa = __builtin_fmaf(ddqc, gR, aRa);
            aIa = __builtin_fmaf(ddqc, gI, aIa);
            s0a = s1; c0a = c1;
        }
        {   // stream b (n1) — independent chain (ILP)
            const float dp = __fadd_rn(__fmul_rn(v.x, q0b), __fmul_rn(v.y, q1b));
            float s1, c1;
            sincos32(dp, &s1, &c1);
            const float ddq  = __fadd_rn(__fmul_rn(dx, q0b), __fmul_rn(dy, q1b));
            const float ddqc = __fsub_rn(__fmul_rn(dy, q0b), __fmul_rn(dx, q1b));
            const bool  m1  = (fabsf(ddq) >= 1e-4f);
            const float inv = __builtin_amdgcn_rcpf(ddq);
            const float dR = __fsub_rn(c0b, c1);
            const float dI = __fsub_rn(s0b, s1);
            const float gR = m1 ? (dR * inv) : s0b;
            const float gI = m1 ? (dI * inv) : (-c0b);
            aRb = __builtin_fmaf(ddqc, gR, aRb);
            aIb = __builtin_fmaf(ddqc, gI, aIb);
            s0b = s1; c0b = c1;
        }

        xp = v.x; yp = v.y;
    }

    float* o = out + (size_t)b * 2 * NPHI;
    o[n0]        = sca * aRa;   // real
    o[NPHI + n0] = sca * aIa;   // imag
    o[n1]        = scb * aRb;
    o[NPHI + n1] = scb * aIb;
}

extern "C" void kernel_launch(void* const* d_in, const int* in_sizes, int n_in,
                              void* d_out, int out_size, void* d_ws, size_t ws_size,
                              hipStream_t stream) {
    const float* points = (const float*)d_in[0];  // [32, 64, 2] fp32
    const float* phi    = (const float*)d_in[1];  // [8192] fp32
    float* out          = (float*)d_out;          // [32, 2, 8192] fp32

    dim3 grid(NPHI / 2 / 256, BATCH);   // 16 x 32 = 512 blocks, 2 waves/SIMD
    scatter_polygon_kernel<<<grid, 256, 0, stream>>>(points, phi, out);
}